// Round 7
// baseline (412.263 us; speedup 1.0000x reference)
//
#include <hip/hip_runtime.h>
#include <math.h>

// ---------------------------------------------------------------------------
// NequIP fused, round 22: 32x32x16 MFMA phase 3 on the fused R15 base.
// R21 acquitted phase 1 (main 241us with pure linear copy-in). Full ledger:
// LDS port (R14), occupancy (R17), B latency (R19), phase-2 VALU (R20),
// phase-1 chain (R21) all acquitted -> phase 3's own issue/wait structure is
// the cost. This round halves its instruction stream: 32x32x16 MFMAs (256 vs
// 512 per wave, 2495 TF rate), A ds_reads 128 vs 256 (slab<3), 4 g-drain
// points vs 8. Phases 1/2 BYTE-IDENTICAL: the 16x16 A-frag image is read by
// 32x32 frags via remapped per-lane addresses (verified on paper vs writer):
//   addr16(mt32,ks; lane) = ((2*mt32+ip)*8 + (ks>>1))*64
//                           + ((lo16 + 32*(ks&1) + 16*lh) ^ (ks>>1))
// C/D: col=lane&31, row=(r&3)+8*(r>>2)+4*lh (doc-verified). i-parity halves
// summed via __shfl_xor(.,16); mt split by ip for duplicate-free stores.
// Predicted: VGPR ~170 no spill, MfmaUtil ~17, main 259 -> ~195-215,
// total ~280-300, absmax 0.015625. Pre-commit: absmax fail => operand-layout
// assumption wrong, revert; main >=240 => instr count acquitted -> deep
// restructure (TE=128 8-wave / persistent producer-consumer) next.
// ---------------------------------------------------------------------------

typedef __attribute__((ext_vector_type(8))) short s8v;     // 8 x bf16 (4 VGPR)
typedef __attribute__((ext_vector_type(16))) float f16v;   // 32x32 acc (16 f32)
typedef unsigned short ushort_t;
typedef unsigned int uint_t;

#define NTHR 256
#define TE 64

__device__ __forceinline__ ushort_t f2bf(float x) {
    uint_t u = __float_as_uint(x);
    u += 0x7fffu + ((u >> 16) & 1u);   // round-to-nearest-even
    return (ushort_t)(u >> 16);
}
__device__ __forceinline__ float bf2f(ushort_t v) {
    return __uint_as_float((uint_t)v << 16);
}

// blocks [0,256): W2 [256][1024] fp32 -> W2bf [1024][256] bf16 (transposed).
// blocks [256,...): histogram of edge_dst into counts.
__global__ void prep_kernel(const float* __restrict__ W2, ushort_t* __restrict__ W2bf,
                            const int* __restrict__ edst, int* __restrict__ counts, int E) {
    if (blockIdx.x < 256) {
        int idx = blockIdx.x * 256 + threadIdx.x;      // 65536 threads, 4 k each
        int n  = idx & 1023;
        int k4 = (idx >> 10) << 2;
        uint_t lo = (uint_t)f2bf(W2[(size_t)(k4 + 0) * 1024 + n]) |
                    ((uint_t)f2bf(W2[(size_t)(k4 + 1) * 1024 + n]) << 16);
        uint_t hi = (uint_t)f2bf(W2[(size_t)(k4 + 2) * 1024 + n]) |
                    ((uint_t)f2bf(W2[(size_t)(k4 + 3) * 1024 + n]) << 16);
        ((uint2*)W2bf)[(n * 256 + k4) >> 2] = make_uint2(lo, hi);
    } else {
        int i = (blockIdx.x - 256) * 256 + threadIdx.x;
        if (i < E) atomicAdd(&counts[edst[i]], 1);
    }
}

// 1 block, 1024 threads: exclusive scan of counts[N] -> offsets[N+1]
__global__ __launch_bounds__(1024)
void scan_kernel(const int* __restrict__ counts, int* __restrict__ offsets, int N) {
    __shared__ int sdata[1024];
    const int t = threadIdx.x;
    const int C = (N + 1023) / 1024;
    const int lo = t * C;
    const int hi = min(lo + C, N);
    int sum = 0;
    for (int i = lo; i < hi; ++i) sum += counts[i];
    sdata[t] = sum;
    __syncthreads();
    for (int s = 1; s < 1024; s <<= 1) {
        int v = (t >= s) ? sdata[t - s] : 0;
        __syncthreads();
        sdata[t] += v;
        __syncthreads();
    }
    int run = sdata[t] - sum;
    for (int i = lo; i < hi; ++i) { offsets[i] = run; run += counts[i]; }
    if (t == 1023) offsets[N] = run;
}

// ---------------- gather: one wave per node; F is bf16 ----------------
__global__ __launch_bounds__(256)
void gather_kernel(const ushort_t* __restrict__ F,
                   const int* __restrict__ offsets,
                   const int* __restrict__ elist,
                   float* __restrict__ out, int N) {
    const int lane = threadIdx.x & 63;
    const int node = (blockIdx.x * 256 + threadIdx.x) >> 6;
    if (node >= N) return;
    const int base = offsets[node];
    const int end  = offsets[node + 1];
    float acc = 0.f;
    for (int j0 = base; j0 < end; j0 += 64) {
        const int rem = min(64, end - j0);
        int myeid = (lane < rem) ? elist[j0 + lane] : 0;
        int j = 0;
        for (; j + 4 <= rem; j += 4) {
            const int a0 = __shfl(myeid, j    );
            const int a1 = __shfl(myeid, j + 1);
            const int a2 = __shfl(myeid, j + 2);
            const int a3 = __shfl(myeid, j + 3);
            const float r0 = bf2f(F[(size_t)a0 * 64 + lane]);
            const float r1 = bf2f(F[(size_t)a1 * 64 + lane]);
            const float r2 = bf2f(F[(size_t)a2 * 64 + lane]);
            const float r3 = bf2f(F[(size_t)a3 * 64 + lane]);
            acc += (r0 + r1) + (r2 + r3);
        }
        for (; j < rem; ++j) {
            const int a = __shfl(myeid, j);
            acc += bf2f(F[(size_t)a * 64 + lane]);
        }
    }
    out[(size_t)node * 64 + lane] = acc;
}

// ---------------- main fused edge kernel (256 thr, 4 waves) ----------------
// Also performs the CSR fill for its own 64 edges.
__global__ __launch_bounds__(NTHR, 2)
void nequip_mfma(const float* __restrict__ nodef,
                 const float* __restrict__ eattr,
                 const float* __restrict__ eemb,
                 const float* __restrict__ W1,
                 const float* __restrict__ b1,
                 const ushort_t* __restrict__ W2bf,
                 const float* __restrict__ b2,
                 const int* __restrict__ esrc,
                 const int* __restrict__ edst,
                 const int* __restrict__ offs,
                 int* __restrict__ cursor,
                 int* __restrict__ elist,
                 ushort_t* __restrict__ F,
                 int E, float CC)
{
    __shared__ __align__(16) ushort_t sAu[TE * 256];   // 32 KB h bf16, A-frag order
    __shared__ __align__(16) float sB2[1024];          // 4 KB
    __shared__ __align__(16) float sEmb[TE * 18];      // 4.5 KB
    __shared__ __align__(16) float sCss[16 * 64];      // coef[i][e] = CC*y0*s
    __shared__ __align__(16) float sCvv[16 * 64];      // CC/sqrt3*(y1.v)
    __shared__ __align__(16) float sCsv[16 * 64];      // CC*s
    __shared__ __align__(16) float sCvs[48 * 64];      // [(i*3+a)][e] = CC*y0*v
    __shared__ __align__(16) float sAttrT[4 * 64];     // [c][e]
    __shared__ __align__(16) float resSS[64 * 16];     // ss partial (4 KB)
    __shared__ __align__(16) float resSV[64 * 16];     // sv partial (4 KB)

    const int t  = threadIdx.x;
    const int e0 = blockIdx.x * TE;

    // ---------------- phase 1: staging + coef tables + CSR fill ----------------
    ((float4*)sB2)[t] = ((const float4*)b2)[t];        // 256 x float4 = 1024
    for (int idx = t; idx < TE * 18; idx += NTHR) {
        size_t g = (size_t)e0 * 18 + idx;
        sEmb[idx] = (g < (size_t)E * 18) ? eemb[g] : 0.f;
    }
    if (t < TE) {
        int ge = e0 + t;
        float4 a = make_float4(0.f, 0.f, 0.f, 0.f);
        if (ge < E) {
            a = *(const float4*)(eattr + (size_t)ge * 4);
            // fused CSR fill for this block's edges
            const int d = edst[ge];
            const int pos = offs[d] + atomicAdd(&cursor[d], 1);
            elist[pos] = ge;
        }
        sAttrT[0 * 64 + t] = a.x; sAttrT[1 * 64 + t] = a.y;
        sAttrT[2 * 64 + t] = a.z; sAttrT[3 * 64 + t] = a.w;
    }
    {   // thread t -> edge e = t>>2, i-quad iq = t&3
        const int e = t >> 2, iq = t & 3;
        const int ge = e0 + e;
        const bool ok = ge < E;
        float y0 = 0.f, y1x = 0.f, y1y = 0.f, y1z = 0.f;
        int src = 0;
        if (ok) {
            float4 a = *(const float4*)(eattr + (size_t)ge * 4);
            y0 = a.x; y1x = a.y; y1y = a.z; y1z = a.w;
            src = esrc[ge];
        }
        const float* xp = nodef + (size_t)src * 64;
        float4 z = make_float4(0.f, 0.f, 0.f, 0.f);
        float4 sv = ok ? *(const float4*)(xp + iq * 4) : z;
        float4 v0 = ok ? *(const float4*)(xp + 16 + iq * 12) : z;
        float4 v1 = ok ? *(const float4*)(xp + 16 + iq * 12 + 4) : z;
        float4 v2 = ok ? *(const float4*)(xp + 16 + iq * 12 + 8) : z;
        const float K3 = CC * 0.57735026918962576f;   // CC/sqrt(3)
        float sarr[4] = { sv.x, sv.y, sv.z, sv.w };
        float varr[12] = { v0.x, v0.y, v0.z, v0.w, v1.x, v1.y, v1.z, v1.w,
                           v2.x, v2.y, v2.z, v2.w };
        #pragma unroll
        for (int j = 0; j < 4; ++j) {
            const int i = iq * 4 + j;
            const float s  = sarr[j];
            const float vx = varr[j * 3 + 0], vy = varr[j * 3 + 1], vz = varr[j * 3 + 2];
            sCss[i * 64 + e] = CC * y0 * s;
            sCvv[i * 64 + e] = K3 * (y1x * vx + y1y * vy + y1z * vz);
            sCsv[i * 64 + e] = CC * s;
            sCvs[(i * 3 + 0) * 64 + e] = CC * y0 * vx;
            sCvs[(i * 3 + 1) * 64 + e] = CC * y0 * vy;
            sCvs[(i * 3 + 2) * 64 + e] = CC * y0 * vz;
        }
    }
    __syncthreads();

    // ---- phase 2: h = silu(emb@W1+b1) -> sAu, 16x16x32 A-frag order ----
    // (BYTE-IDENTICAL to the verified R15 code)
    {
        const int p = t & 127;         // column pair p -> cols 2p, 2p+1
        const int ehalf = t >> 7;
        const int n0 = 2 * p;
        float w1a[18], w1b[18];
        #pragma unroll
        for (int m = 0; m < 18; ++m) {
            float2 wv = *(const float2*)(W1 + m * 256 + n0);
            w1a[m] = wv.x; w1b[m] = wv.y;
        }
        const float2 bv = *(const float2*)(b1 + n0);
        const int kk = p >> 4;                       // k-iter (0..7)
        const int lhi = 16 * ((p >> 2) & 3);
        const int wsub = p & 3;                      // uint slot within 16B frag
        uint_t* sA32 = (uint_t*)sAu;
        for (int er = 0; er < 32; ++er) {
            const int e = ehalf * 32 + er;
            float a0 = bv.x, a1 = bv.y;
            const float* ep = sEmb + e * 18;
            #pragma unroll
            for (int m = 0; m < 18; ++m) {
                const float em = ep[m];
                a0 = fmaf(em, w1a[m], a0);
                a1 = fmaf(em, w1b[m], a1);
            }
            a0 = a0 / (1.f + __expf(-a0));          // silu
            a1 = a1 / (1.f + __expf(-a1));
            const uint_t pk = (uint_t)f2bf(a0) | ((uint_t)f2bf(a1) << 16);
            const int lane_sw = ((e & 15) + lhi) ^ kk;
            sA32[(((e >> 4) * 8 + kk) * 64 + lane_sw) * 4 + wsub] = pk;
        }
    }
    __syncthreads();

    // ---------------- phase 3: 32x32x16 MFMA; wave = slab ----------------
    const int lane = t & 63;
    const int slab = t >> 6;          // 0:ss 1:vv 2:sv 3:vs
    const int lo16 = lane & 15;       // output col jj / A row low bits
    const int ip   = (lane >> 4) & 1; // A 16-subtile parity = i-parity in epi
    const int lh   = lane >> 5;       // k-octet half; e-offset 4*lh in C/D
    const int col  = lane & 31;       // output column within 32-wide n-tile

    float pS[2][16] = {{0.f}};        // slab<3 partials [mt][reg]
    float pV[3][2][16] = {{{0.f}}};   // vs partials [a][mt][reg]

    if (slab < 3) {
        const float* C = (slab == 0) ? sCss : (slab == 1) ? sCvv : sCsv;
        #pragma unroll 1
        for (int g = 0; g < 4; ++g) {
            const int n0 = slab * 256 + (2 * g) * 32;
            const ushort_t* Bp0 = W2bf + (size_t)(n0 + col) * 256 + lh * 8;
            const ushort_t* Bp1 = Bp0 + (size_t)32 * 256;
            f16v c00, c01, c10, c11;
            {
                const float bz0 = sB2[n0 + col];
                const float bz1 = sB2[n0 + 32 + col];
                #pragma unroll
                for (int r = 0; r < 16; ++r) { c00[r] = bz0; c01[r] = bz1; c10[r] = bz0; c11[r] = bz1; }
            }
            #pragma unroll
            for (int ks = 0; ks < 16; ++ks) {
                const int kk16 = ks >> 1;
                const int lsw = (lo16 + 32 * (ks & 1) + 16 * lh) ^ kk16;
                const s8v a0 = *(const s8v*)(sAu + (((0 + ip) * 8 + kk16) * 64 + lsw) * 8);
                const s8v a1 = *(const s8v*)(sAu + (((2 + ip) * 8 + kk16) * 64 + lsw) * 8);
                const s8v b0 = *(const s8v*)(Bp0 + ks * 16);
                const s8v b1 = *(const s8v*)(Bp1 + ks * 16);
                c00 = __builtin_amdgcn_mfma_f32_32x32x16_bf16(a0, b0, c00, 0, 0, 0);
                c01 = __builtin_amdgcn_mfma_f32_32x32x16_bf16(a0, b1, c01, 0, 0, 0);
                c10 = __builtin_amdgcn_mfma_f32_32x32x16_bf16(a1, b0, c10, 0, 0, 0);
                c11 = __builtin_amdgcn_mfma_f32_32x32x16_bf16(a1, b1, c11, 0, 0, 0);
            }
            // contraction: lane's i values are 4g+ip (nt0) and 4g+2+ip (nt1)
            const float* Ci0 = C + (4 * g + ip) * 64 + 4 * lh;
            const float* Ci1 = C + (4 * g + 2 + ip) * 64 + 4 * lh;
            #pragma unroll
            for (int q = 0; q < 4; ++q) {
                const float4 cA0 = *(const float4*)(Ci0 + 8 * q);        // mt0, nt0
                const float4 cA1 = *(const float4*)(Ci0 + 32 + 8 * q);   // mt1, nt0
                const float4 cB0 = *(const float4*)(Ci1 + 8 * q);        // mt0, nt1
                const float4 cB1 = *(const float4*)(Ci1 + 32 + 8 * q);   // mt1, nt1
                pS[0][4*q+0] += cA0.x * c00[4*q+0] + cB0.x * c01[4*q+0];
                pS[0][4*q+1] += cA0.y * c00[4*q+1] + cB0.y * c01[4*q+1];
                pS[0][4*q+2] += cA0.z * c00[4*q+2] + cB0.z * c01[4*q+2];
                pS[0][4*q+3] += cA0.w * c00[4*q+3] + cB0.w * c01[4*q+3];
                pS[1][4*q+0] += cA1.x * c10[4*q+0] + cB1.x * c11[4*q+0];
                pS[1][4*q+1] += cA1.y * c10[4*q+1] + cB1.y * c11[4*q+1];
                pS[1][4*q+2] += cA1.z * c10[4*q+2] + cB1.z * c11[4*q+2];
                pS[1][4*q+3] += cA1.w * c10[4*q+3] + cB1.w * c11[4*q+3];
            }
        }
        // i-parity reduction: lane l and l^16 hold complementary i-halves
        #pragma unroll
        for (int mt = 0; mt < 2; ++mt)
            #pragma unroll
            for (int r = 0; r < 16; ++r)
                pS[mt][r] += __shfl_xor(pS[mt][r], 16);
    } else {
        // ---- vs: 1 n-tile per g (8 g's) to bound registers ----
        #pragma unroll 1
        for (int g = 0; g < 8; ++g) {
            const int n0 = 3 * 256 + g * 32;
            const ushort_t* Bp = W2bf + (size_t)(n0 + col) * 256 + lh * 8;
            f16v c0, c1;
            {
                const float bz = sB2[n0 + col];
                #pragma unroll
                for (int r = 0; r < 16; ++r) { c0[r] = bz; c1[r] = bz; }
            }
            #pragma unroll
            for (int ks = 0; ks < 16; ++ks) {
                const int kk16 = ks >> 1;
                const int lsw = (lo16 + 32 * (ks & 1) + 16 * lh) ^ kk16;
                const s8v a0 = *(const s8v*)(sAu + (((0 + ip) * 8 + kk16) * 64 + lsw) * 8);
                const s8v a1 = *(const s8v*)(sAu + (((2 + ip) * 8 + kk16) * 64 + lsw) * 8);
                const s8v b  = *(const s8v*)(Bp + ks * 16);
                c0 = __builtin_amdgcn_mfma_f32_32x32x16_bf16(a0, b, c0, 0, 0, 0);
                c1 = __builtin_amdgcn_mfma_f32_32x32x16_bf16(a1, b, c1, 0, 0, 0);
            }
            const int ib = (2 * g + ip) * 3;
            #pragma unroll
            for (int a = 0; a < 3; ++a) {
                const float* Cv = sCvs + (ib + a) * 64 + 4 * lh;
                #pragma unroll
                for (int q = 0; q < 4; ++q) {
                    const float4 c0f = *(const float4*)(Cv + 8 * q);
                    const float4 c1f = *(const float4*)(Cv + 32 + 8 * q);
                    pV[a][0][4*q+0] += c0f.x * c0[4*q+0];
                    pV[a][0][4*q+1] += c0f.y * c0[4*q+1];
                    pV[a][0][4*q+2] += c0f.z * c0[4*q+2];
                    pV[a][0][4*q+3] += c0f.w * c0[4*q+3];
                    pV[a][1][4*q+0] += c1f.x * c1[4*q+0];
                    pV[a][1][4*q+1] += c1f.y * c1[4*q+1];
                    pV[a][1][4*q+2] += c1f.z * c1[4*q+2];
                    pV[a][1][4*q+3] += c1f.w * c1[4*q+3];
                }
            }
        }
        #pragma unroll
        for (int a = 0; a < 3; ++a)
            #pragma unroll
            for (int mt = 0; mt < 2; ++mt)
                #pragma unroll
                for (int r = 0; r < 16; ++r)
                    pV[a][mt][r] += __shfl_xor(pV[a][mt][r], 16);
    }

    // publish ss / sv partials (mt split by ip -> duplicate-free)
    if (slab == 0 || slab == 2) {
        float* res = (slab == 0) ? resSS : resSV;
        if (ip == 0) {
            #pragma unroll
            for (int r = 0; r < 16; ++r)
                res[(4 * lh + 8 * (r >> 2) + (r & 3)) * 16 + lo16] = pS[0][r];
        } else {
            #pragma unroll
            for (int r = 0; r < 16; ++r)
                res[(32 + 4 * lh + 8 * (r >> 2) + (r & 3)) * 16 + lo16] = pS[1][r];
        }
    }
    __syncthreads();

    // ---------------- combine + store to F (bf16) ----------------
    if (slab == 1) {          // out_s = resSS(ss) + vv partial
        if (ip == 0) {
            #pragma unroll
            for (int r = 0; r < 16; ++r) {
                const int e = 4 * lh + 8 * (r >> 2) + (r & 3);
                const int ge = e0 + e;
                if (ge < E) F[(size_t)ge * 64 + lo16] = f2bf(resSS[e * 16 + lo16] + pS[0][r]);
            }
        } else {
            #pragma unroll
            for (int r = 0; r < 16; ++r) {
                const int e = 32 + 4 * lh + 8 * (r >> 2) + (r & 3);
                const int ge = e0 + e;
                if (ge < E) F[(size_t)ge * 64 + lo16] = f2bf(resSS[e * 16 + lo16] + pS[1][r]);
            }
        }
    } else if (slab == 3) {   // out_v[a] = y1[a]*resSV(sv) + vs partial
        if (ip == 0) {
            #pragma unroll
            for (int r = 0; r < 16; ++r) {
                const int e = 4 * lh + 8 * (r >> 2) + (r & 3);
                const int ge = e0 + e;
                const float sv = resSV[e * 16 + lo16];
                if (ge < E) {
                    #pragma unroll
                    for (int a = 0; a < 3; ++a)
                        F[(size_t)ge * 64 + 16 + lo16 * 3 + a] =
                            f2bf(fmaf(sAttrT[(1 + a) * 64 + e], sv, pV[a][0][r]));
                }
            }
        } else {
            #pragma unroll
            for (int r = 0; r < 16; ++r) {
                const int e = 32 + 4 * lh + 8 * (r >> 2) + (r & 3);
                const int ge = e0 + e;
                const float sv = resSV[e * 16 + lo16];
                if (ge < E) {
                    #pragma unroll
                    for (int a = 0; a < 3; ++a)
                        F[(size_t)ge * 64 + 16 + lo16 * 3 + a] =
                            f2bf(fmaf(sAttrT[(1 + a) * 64 + e], sv, pV[a][1][r]));
                }
            }
        }
    }
}

extern "C" void kernel_launch(void* const* d_in, const int* in_sizes, int n_in,
                              void* d_out, int out_size, void* d_ws, size_t ws_size,
                              hipStream_t stream)
{
    const float* node_features = (const float*)d_in[0];
    const float* edge_attr     = (const float*)d_in[1];
    const float* edge_emb      = (const float*)d_in[2];
    const float* W1            = (const float*)d_in[3];
    const float* b1            = (const float*)d_in[4];
    const float* W2            = (const float*)d_in[5];
    const float* b2            = (const float*)d_in[6];
    const int*   edge_src      = (const int*)d_in[7];
    const int*   edge_dst      = (const int*)d_in[8];
    float*       out           = (float*)d_out;

    const int E = in_sizes[7];
    const int N = out_size / 64;
    const float num_neigh = (float)E / (float)N;
    const float CC = 0.17677669529663689f / sqrtf(num_neigh);

    // ---- workspace layout ----
    char* ws = (char*)d_ws;
    size_t off = 0;
    auto alloc = [&](size_t bytes) { char* p = ws + off; off = (off + bytes + 255) & ~(size_t)255; return p; };
    ushort_t* W2bf   = (ushort_t*)alloc((size_t)1024 * 256 * 2);
    int*      counts = (int*)alloc((size_t)2 * N * 4);    // counts[N] + cursor[N]
    int*      cursor = counts + N;
    int*      offs   = (int*)alloc((size_t)(N + 1) * 4);
    int*      elist  = (int*)alloc((size_t)E * 4);
    ushort_t* F      = (ushort_t*)alloc((size_t)E * 64 * 2);
    (void)ws_size;

    hipMemsetAsync(counts, 0, (size_t)2 * N * 4, stream);

    const int histBlocks = (E + 255) / 256;
    prep_kernel<<<256 + histBlocks, 256, 0, stream>>>(W2, W2bf, edge_dst, counts, E);
    scan_kernel<<<1, 1024, 0, stream>>>(counts, offs, N);

    const int blocks = (E + TE - 1) / TE;
    nequip_mfma<<<blocks, NTHR, 0, stream>>>(
        node_features, edge_attr, edge_emb, W1, b1, W2bf, b2,
        edge_src, edge_dst, offs, cursor, elist, F, E, CC);

    gather_kernel<<<(N + 3) / 4, 256, 0, stream>>>(F, offs, elist, out, N);
}